// Round 1
// baseline (2481.708 us; speedup 1.0000x reference)
//
#include <hip/hip_runtime.h>
#include <hip/hip_bf16.h>
#include <stdint.h>

#define B_ 32
#define T_ 128
#define H_ 1024
#define V_ 32000

typedef unsigned short u16;
typedef __attribute__((ext_vector_type(8))) short short8;
typedef __attribute__((ext_vector_type(4))) float f32x4;

static __device__ __forceinline__ u16 f2bf(float f) {
    uint32_t u = __float_as_uint(f);
    uint32_t r = (u + 0x7FFFu + ((u >> 16) & 1u)) >> 16;
    return (u16)r;
}

static __device__ __forceinline__ float sigmf(float x) {
    return 1.0f / (1.0f + __expf(-x));
}

// ---------------------------------------------------------------------------
// Prep: W_comb = W_ih[:,1:] + W_hh  (bf16), wx = W_ih[:,0], biasc = b_ih+b_hh
// ---------------------------------------------------------------------------
__global__ void prep_w(const float* __restrict__ Wih, const float* __restrict__ Whh,
                       const float* __restrict__ bih, const float* __restrict__ bhh,
                       u16* __restrict__ Wc, float* __restrict__ wx, float* __restrict__ biasc) {
    int idx = blockIdx.x * 256 + threadIdx.x;      // 4096*1024 threads
    int r = idx >> 10, k = idx & 1023;
    float v = Wih[r * (H_ + 1) + 1 + k] + Whh[idx];
    Wc[idx] = f2bf(v);
    if (k == 0) {
        wx[r] = Wih[r * (H_ + 1)];
        biasc[r] = bih[r] + bhh[r];
    }
}

// W_out fp32 -> bf16
__global__ void prep_wout(const float* __restrict__ Wout, u16* __restrict__ Wo) {
    long long i = (long long)(blockIdx.x) * 256 + threadIdx.x;   // x4 elements each
    f32x4 v = *(const f32x4*)(Wout + i * 4);
    uint2 o;
    o.x = (uint32_t)f2bf(v[0]) | ((uint32_t)f2bf(v[1]) << 16);
    o.y = (uint32_t)f2bf(v[2]) | ((uint32_t)f2bf(v[3]) << 16);
    *(uint2*)(Wo + i * 4) = o;
}

// ---------------------------------------------------------------------------
// Init: h0 = enc @ W_h^T (bf16), c0 = enc @ W_c^T (fp32). One wave per output.
// ---------------------------------------------------------------------------
__global__ void init_hc(const float* __restrict__ enc, const float* __restrict__ Wh,
                        const float* __restrict__ Wcp, u16* __restrict__ h0,
                        float* __restrict__ c0) {
    int gwid = (blockIdx.x * 256 + threadIdx.x) >> 6;   // 65536 waves
    int lane = threadIdx.x & 63;
    int sel = gwid >> 15;                // 0: h, 1: c
    int rem = gwid & 32767;
    int b = rem >> 10, j = rem & 1023;
    const float* W = sel ? Wcp : Wh;
    const float* wrow = W + (size_t)j * H_;
    const float* erow = enc + (size_t)b * H_;
    float acc = 0.f;
#pragma unroll
    for (int it = 0; it < 4; ++it) {
        int k = (it * 64 + lane) * 4;
        f32x4 wv = *(const f32x4*)(wrow + k);
        f32x4 ev = *(const f32x4*)(erow + k);
        acc += wv[0] * ev[0] + wv[1] * ev[1] + wv[2] * ev[2] + wv[3] * ev[3];
    }
#pragma unroll
    for (int s = 32; s >= 1; s >>= 1) acc += __shfl_xor(acc, s, 64);
    if (lane == 0) {
        if (sel) c0[b * H_ + j] = acc;
        else     h0[b * H_ + j] = f2bf(acc);
    }
}

// ---------------------------------------------------------------------------
// One LSTM step. 64 blocks x 256 threads. Block owns j in [j0, j0+16).
// Wave g (0..3) computes gate-type g rows via MFMA:
//   gates[row=g*H+j][b] = sum_k W_comb[row][k] * h_prev[b][k]
// Then pointwise update of c (fp32, in place) and h -> A[(b*T+t)*H + j] (bf16).
// ---------------------------------------------------------------------------
__global__ __launch_bounds__(256) void lstm_step(
    const u16* __restrict__ Wc, const float* __restrict__ wx,
    const float* __restrict__ biasc, const u16* __restrict__ h0,
    const float* __restrict__ y, u16* __restrict__ A, float* __restrict__ c, int t) {
    __shared__ float ex[4][16][32];
    int tid = threadIdx.x;
    int lane = tid & 63;
    int g = tid >> 6;
    int j0 = blockIdx.x * 16;

    const u16* hprev = (t == 0) ? h0 : (A + (size_t)(t - 1) * H_);
    int bstride = (t == 0) ? H_ : (T_ * H_);

    int rowbase = g * H_ + j0;
    int arow = rowbase + (lane & 15);
    int kc = (lane >> 4) * 8;
    const u16* aptr = Wc + (size_t)arow * H_ + kc;
    int bn0 = lane & 15;
    int bn1 = 16 + (lane & 15);
    const u16* bptr0 = hprev + (size_t)bn0 * bstride + kc;
    const u16* bptr1 = hprev + (size_t)bn1 * bstride + kc;

    f32x4 acc0 = {0.f, 0.f, 0.f, 0.f};
    f32x4 acc1 = {0.f, 0.f, 0.f, 0.f};
#pragma unroll 4
    for (int ks = 0; ks < 32; ++ks) {
        short8 a  = *(const short8*)(aptr + ks * 32);
        short8 b0 = *(const short8*)(bptr0 + ks * 32);
        short8 b1 = *(const short8*)(bptr1 + ks * 32);
        acc0 = __builtin_amdgcn_mfma_f32_16x16x32_bf16(a, b0, acc0, 0, 0, 0);
        acc1 = __builtin_amdgcn_mfma_f32_16x16x32_bf16(a, b1, acc1, 0, 0, 0);
    }

    // Scatter gate pre-activations (+ x and bias terms) to LDS.
    int jloc0 = (lane >> 4) * 4;
#pragma unroll
    for (int r = 0; r < 4; ++r) {
        int jloc = jloc0 + r;
        int row = rowbase + jloc;
        float wxr = wx[row], br = biasc[row];
        ex[g][jloc][bn0] = acc0[r] + wxr * y[bn0 * T_ + t] + br;
        ex[g][jloc][bn1] = acc1[r] + wxr * y[bn1 * T_ + t] + br;
    }
    __syncthreads();

    // Pointwise LSTM cell update: 512 (j,b) pairs, 2 per thread.
#pragma unroll
    for (int p = tid; p < 512; p += 256) {
        int jl = p >> 5, b = p & 31;
        float iv = sigmf(ex[0][jl][b]);
        float fv = sigmf(ex[1][jl][b]);
        float gv = tanhf(ex[2][jl][b]);
        float ov = sigmf(ex[3][jl][b]);
        int j = j0 + jl;
        float cv = fv * c[b * H_ + j] + iv * gv;
        c[b * H_ + j] = cv;
        float hv = ov * tanhf(cv);
        A[((size_t)b * T_ + t) * H_ + j] = f2bf(hv);
    }
}

// ---------------------------------------------------------------------------
// Output GEMM: C[m][n] = sum_k A[m][k] * Wo[n][k] + b_out[n]
// m = b*T + t (M=4096), n = vocab (N=32000), K=1024.
// 128x128 tile per block (4 waves, each 64x64 via 4x4 MFMA 16x16x32 frags).
// Write to out[b][n][t] (fp32), 16B-aligned float4 stores.
// ---------------------------------------------------------------------------
__global__ __launch_bounds__(256) void gemm_out(
    const u16* __restrict__ A, const u16* __restrict__ Wo,
    const float* __restrict__ bout, float* __restrict__ out) {
    __shared__ u16 As[128 * 32];
    __shared__ u16 Bs[128 * 32];

    int idx = blockIdx.x;
    int mb = idx & 31;       // 32 m-blocks (== batch b)
    int nb = idx >> 5;       // 250 n-blocks; consecutive idx share nb -> W_out panel reuse
    int m0 = mb * 128, n0 = nb * 128;

    int tid = threadIdx.x, lane = tid & 63, wid = tid >> 6;
    int wm = wid >> 1, wn = wid & 1;

    f32x4 acc[4][4] = {};

    int srow = tid >> 2;            // 0..63
    int scol = (tid & 3) * 8;       // k-offset within 32-chunk
    const u16* Ag = A + (size_t)(m0 + srow) * H_ + scol;
    const u16* Bg = Wo + (size_t)(n0 + srow) * H_ + scol;

    int kc = (lane >> 4) * 8;
    int frow = lane & 15;

    for (int ks = 0; ks < 32; ++ks) {
        int k0 = ks * 32;
        short8 av0 = *(const short8*)(Ag + k0);
        short8 av1 = *(const short8*)(Ag + (size_t)64 * H_ + k0);
        short8 bv0 = *(const short8*)(Bg + k0);
        short8 bv1 = *(const short8*)(Bg + (size_t)64 * H_ + k0);
        __syncthreads();   // previous iter's frag reads done before overwrite
        *(short8*)(&As[srow * 32 + scol]) = av0;
        *(short8*)(&As[(srow + 64) * 32 + scol]) = av1;
        *(short8*)(&Bs[srow * 32 + scol]) = bv0;
        *(short8*)(&Bs[(srow + 64) * 32 + scol]) = bv1;
        __syncthreads();

        short8 af[4], bf[4];
#pragma unroll
        for (int mt = 0; mt < 4; ++mt)
            af[mt] = *(const short8*)(&As[(wm * 64 + mt * 16 + frow) * 32 + kc]);
#pragma unroll
        for (int nt = 0; nt < 4; ++nt)
            bf[nt] = *(const short8*)(&Bs[(wn * 64 + nt * 16 + frow) * 32 + kc]);
#pragma unroll
        for (int mt = 0; mt < 4; ++mt)
#pragma unroll
            for (int nt = 0; nt < 4; ++nt)
                acc[mt][nt] = __builtin_amdgcn_mfma_f32_16x16x32_bf16(af[mt], bf[nt], acc[mt][nt], 0, 0, 0);
    }

    // Epilogue: C row = t index within batch mb, col = vocab n.
    int b = mb;
#pragma unroll
    for (int nt = 0; nt < 4; ++nt) {
        int n = n0 + wn * 64 + nt * 16 + (lane & 15);
        float bias = bout[n];
#pragma unroll
        for (int mt = 0; mt < 4; ++mt) {
            int trow = wm * 64 + mt * 16 + (lane >> 4) * 4;
            f32x4 v = acc[mt][nt];
            v[0] += bias; v[1] += bias; v[2] += bias; v[3] += bias;
            float* dst = out + ((size_t)b * V_ + n) * T_ + trow;
            *(f32x4*)dst = v;
        }
    }
}

// ---------------------------------------------------------------------------
extern "C" void kernel_launch(void* const* d_in, const int* in_sizes, int n_in,
                              void* d_out, int out_size, void* d_ws, size_t ws_size,
                              hipStream_t stream) {
    const float* y    = (const float*)d_in[0];   // [B,T]
    const float* enc  = (const float*)d_in[1];   // [B,H]
    const float* Wh   = (const float*)d_in[2];   // [H,H]
    const float* Wcp  = (const float*)d_in[3];   // [H,H]
    const float* Wih  = (const float*)d_in[4];   // [4H,1+H]
    const float* Whh  = (const float*)d_in[5];   // [4H,H]
    const float* bih  = (const float*)d_in[6];   // [4H]
    const float* bhh  = (const float*)d_in[7];   // [4H]
    const float* Wout = (const float*)d_in[8];   // [V,H]
    const float* bout = (const float*)d_in[9];   // [V]

    uint8_t* ws = (uint8_t*)d_ws;
    u16*  Wcomb = (u16*)ws;                                   // 4096*1024*2  = 8,388,608
    u16*  Wo    = (u16*)(ws + 8388608);                       // 32000*1024*2 = 65,536,000
    float* wx    = (float*)(ws + 8388608 + 65536000);         // 4096*4
    float* biasc = wx + 4096;                                 // 4096*4
    u16*  h0    = (u16*)(biasc + 4096);                       // 32*1024*2
    float* c     = (float*)(h0 + 32 * 1024);                  // 32*1024*4
    u16*  A     = (u16*)(c + 32 * 1024);                      // 4096*1024*2

    prep_w<<<16384, 256, 0, stream>>>(Wih, Whh, bih, bhh, Wcomb, wx, biasc);
    prep_wout<<<32000, 256, 0, stream>>>(Wout, Wo);
    init_hc<<<16384, 256, 0, stream>>>(enc, Wh, Wcp, h0, c);

    for (int t = 0; t < T_; ++t)
        lstm_step<<<64, 256, 0, stream>>>(Wcomb, wx, biasc, h0, y, A, c, t);

    gemm_out<<<8000, 256, 0, stream>>>(A, Wo, bout, (float*)d_out);
}

// Round 2
// 1317.322 us; speedup vs baseline: 1.8839x; 1.8839x over previous
//
#include <hip/hip_runtime.h>
#include <hip/hip_bf16.h>
#include <stdint.h>

#define B_ 32
#define T_ 128
#define H_ 1024
#define V_ 32000
#define NBLK_REC 64

typedef unsigned short u16;
typedef __attribute__((ext_vector_type(8))) short short8;
typedef __attribute__((ext_vector_type(4))) float f32x4;

static __device__ __forceinline__ u16 f2bf(float f) {
    uint32_t u = __float_as_uint(f);
    uint32_t r = (u + 0x7FFFu + ((u >> 16) & 1u)) >> 16;
    return (u16)r;
}

static __device__ __forceinline__ float sigmf(float x) {
    return 1.0f / (1.0f + __expf(-x));
}

static __device__ __forceinline__ float tanh_f(float x) {
    x = fminf(fmaxf(x, -20.f), 20.f);
    float e = __expf(2.f * x);
    return (e - 1.f) / (e + 1.f);
}

// ---------------------------------------------------------------------------
// Prep: W_comb = W_ih[:,1:] + W_hh  (bf16), wx = W_ih[:,0], biasc = b_ih+b_hh
// Also zeroes the grid-barrier counter (must be re-zeroed every launch).
// ---------------------------------------------------------------------------
__global__ void prep_w(const float* __restrict__ Wih, const float* __restrict__ Whh,
                       const float* __restrict__ bih, const float* __restrict__ bhh,
                       u16* __restrict__ Wc, float* __restrict__ wx, float* __restrict__ biasc,
                       unsigned* __restrict__ bar) {
    int idx = blockIdx.x * 256 + threadIdx.x;      // 4096*1024 threads
    int r = idx >> 10, k = idx & 1023;
    float v = Wih[r * (H_ + 1) + 1 + k] + Whh[idx];
    Wc[idx] = f2bf(v);
    if (k == 0) {
        wx[r] = Wih[r * (H_ + 1)];
        biasc[r] = bih[r] + bhh[r];
    }
    if (idx == 0) bar[0] = 0u;
}

// W_out fp32 -> bf16
__global__ void prep_wout(const float* __restrict__ Wout, u16* __restrict__ Wo) {
    long long i = (long long)(blockIdx.x) * 256 + threadIdx.x;   // x4 elements each
    f32x4 v = *(const f32x4*)(Wout + i * 4);
    uint2 o;
    o.x = (uint32_t)f2bf(v[0]) | ((uint32_t)f2bf(v[1]) << 16);
    o.y = (uint32_t)f2bf(v[2]) | ((uint32_t)f2bf(v[3]) << 16);
    *(uint2*)(Wo + i * 4) = o;
}

// ---------------------------------------------------------------------------
// Init: h0 = enc @ W_h^T (bf16), c0 = enc @ W_c^T (fp32). One wave per output.
// ---------------------------------------------------------------------------
__global__ void init_hc(const float* __restrict__ enc, const float* __restrict__ Wh,
                        const float* __restrict__ Wcp, u16* __restrict__ h0,
                        float* __restrict__ c0) {
    int gwid = (blockIdx.x * 256 + threadIdx.x) >> 6;   // 65536 waves
    int lane = threadIdx.x & 63;
    int sel = gwid >> 15;                // 0: h, 1: c
    int rem = gwid & 32767;
    int b = rem >> 10, j = rem & 1023;
    const float* W = sel ? Wcp : Wh;
    const float* wrow = W + (size_t)j * H_;
    const float* erow = enc + (size_t)b * H_;
    float acc = 0.f;
#pragma unroll
    for (int it = 0; it < 4; ++it) {
        int k = (it * 64 + lane) * 4;
        f32x4 wv = *(const f32x4*)(wrow + k);
        f32x4 ev = *(const f32x4*)(erow + k);
        acc += wv[0] * ev[0] + wv[1] * ev[1] + wv[2] * ev[2] + wv[3] * ev[3];
    }
#pragma unroll
    for (int s = 32; s >= 1; s >>= 1) acc += __shfl_xor(acc, s, 64);
    if (lane == 0) {
        if (sel) c0[b * H_ + j] = acc;
        else     h0[b * H_ + j] = f2bf(acc);
    }
}

// ---------------------------------------------------------------------------
// Persistent LSTM recurrence. 64 blocks x 256 threads; block owns j0=bid*16
// (16 j columns -> 64 gate rows). Weights held in REGISTERS for all 128 steps
// (each wave owns K-slice kw*256..+256: afr[4 gates][8 ksteps] short8).
// Per step: load h_prev fragments (plain b128 from fresh lines), MFMA,
// K-reduce across waves in LDS, pointwise cell update (c in LDS),
// write h_t via agent-scope write-through stores, grid barrier.
// ---------------------------------------------------------------------------
__global__ __launch_bounds__(256, 1) void lstm_persist(
    const u16* __restrict__ Wc, const float* __restrict__ wx,
    const float* __restrict__ biasc, const u16* __restrict__ h0,
    const float* __restrict__ c0, const float* __restrict__ y,
    u16* __restrict__ A, unsigned* __restrict__ bar) {
    __shared__ float red[4][64 * 33];    // per-wave partial sums, padded (33)
    __shared__ float cs[16][32];         // cell state [jl][b]
    __shared__ float wxs[64], bcs[64];   // per-row x-weight / bias

    int tid = threadIdx.x;
    int lane = tid & 63;
    int kw = tid >> 6;                   // wave id = K-slice
    int bid = blockIdx.x;
    int j0 = bid * 16;
    int jl = lane & 15;                  // A-row / B-col lane index
    int kc = (lane >> 4) * 8;            // k-offset within 32-chunk
    int q = tid >> 5, b = tid & 31;      // pointwise mapping

    // ---- one-time: weights to registers ----
    short8 afr[4][8];
    {
        const u16* abase = Wc + (size_t)(j0 + jl) * H_ + kw * 256 + kc;
#pragma unroll
        for (int g = 0; g < 4; ++g)
#pragma unroll
            for (int ks = 0; ks < 8; ++ks)
                afr[g][ks] = *(const short8*)(abase + (size_t)g * H_ * H_ + ks * 32);
    }
    // ---- one-time: stage wx/bias/c0 into LDS ----
    if (tid < 64) {
        int g = tid >> 4, jj = tid & 15;
        wxs[tid] = wx[(size_t)g * H_ + j0 + jj];
        bcs[tid] = biasc[(size_t)g * H_ + j0 + jj];
    }
    cs[2 * q][b]     = c0[(size_t)b * H_ + j0 + 2 * q];
    cs[2 * q + 1][b] = c0[(size_t)b * H_ + j0 + 2 * q + 1];
    __syncthreads();

    for (int t = 0; t < T_; ++t) {
        const u16* hp = (t == 0) ? h0 : (A + (size_t)(t - 1) * H_);
        size_t bst = (t == 0) ? (size_t)H_ : (size_t)T_ * H_;

        // ---- load B-frags (h_prev) and MFMA ----
        short8 bfr0[8], bfr1[8];
        {
            const u16* hb = hp + (size_t)jl * bst + kw * 256 + kc;
#pragma unroll
            for (int ks = 0; ks < 8; ++ks) {
                bfr0[ks] = *(const short8*)(hb + ks * 32);
                bfr1[ks] = *(const short8*)(hb + (size_t)16 * bst + ks * 32);
            }
        }
        f32x4 acc[4][2] = {};
#pragma unroll
        for (int ks = 0; ks < 8; ++ks) {
#pragma unroll
            for (int g = 0; g < 4; ++g) {
                acc[g][0] = __builtin_amdgcn_mfma_f32_16x16x32_bf16(afr[g][ks], bfr0[ks], acc[g][0], 0, 0, 0);
                acc[g][1] = __builtin_amdgcn_mfma_f32_16x16x32_bf16(afr[g][ks], bfr1[ks], acc[g][1], 0, 0, 0);
            }
        }
        // ---- partials to LDS ----
        int r0 = (lane >> 4) * 4;
#pragma unroll
        for (int g = 0; g < 4; ++g)
#pragma unroll
            for (int bt = 0; bt < 2; ++bt)
#pragma unroll
                for (int r = 0; r < 4; ++r)
                    red[kw][(g * 16 + r0 + r) * 33 + bt * 16 + jl] = acc[g][bt][r];
        __syncthreads();

        // ---- pointwise cell update; write h_t (agent-scope, write-through) ----
        {
            float yv = y[b * T_ + t];
            float hv[2];
#pragma unroll
            for (int s = 0; s < 2; ++s) {
                int jlx = 2 * q + s;
                float pre[4];
#pragma unroll
                for (int g = 0; g < 4; ++g) {
                    int row = (g * 16 + jlx) * 33 + b;
                    pre[g] = red[0][row] + red[1][row] + red[2][row] + red[3][row]
                           + wxs[g * 16 + jlx] * yv + bcs[g * 16 + jlx];
                }
                float iv = sigmf(pre[0]);
                float fv = sigmf(pre[1]);
                float gv = tanh_f(pre[2]);
                float ov = sigmf(pre[3]);
                float cv = fv * cs[jlx][b] + iv * gv;
                cs[jlx][b] = cv;
                hv[s] = ov * tanh_f(cv);
            }
            uint32_t pk = (uint32_t)f2bf(hv[0]) | ((uint32_t)f2bf(hv[1]) << 16);
            __hip_atomic_store((uint32_t*)(A + ((size_t)b * T_ + t) * H_ + j0 + 2 * q),
                               pk, __ATOMIC_RELAXED, __HIP_MEMORY_SCOPE_AGENT);
        }
        __syncthreads();   // all waves drained (vmcnt0 before s_barrier) + red reads done

        // ---- grid barrier: monotone counter, no reset ----
        if (tid == 0) {
            __hip_atomic_fetch_add(&bar[0], 1u, __ATOMIC_RELEASE, __HIP_MEMORY_SCOPE_AGENT);
            unsigned target = (unsigned)NBLK_REC * (unsigned)(t + 1);
            int guard = 0;
            while (__hip_atomic_load(&bar[0], __ATOMIC_RELAXED, __HIP_MEMORY_SCOPE_AGENT) < target) {
                __builtin_amdgcn_s_sleep(1);
                if (++guard > 50000000) break;   // safety: never triggers when co-resident
            }
            __atomic_signal_fence(__ATOMIC_ACQUIRE);
        }
        __syncthreads();
    }
}

// ---------------------------------------------------------------------------
// Output GEMM: C[m][n] = sum_k A[m][k] * Wo[n][k] + b_out[n]
// 128x128 tile per block. XCD-bijective swizzle groups the 32 blocks sharing
// a W_out panel onto one XCD; LDS row stride 40 (80 B, 16B-aligned) breaks
// the 8-way bank conflict of stride-32.
// ---------------------------------------------------------------------------
#define LSTR 40
__global__ __launch_bounds__(256) void gemm_out(
    const u16* __restrict__ A, const u16* __restrict__ Wo,
    const float* __restrict__ bout, float* __restrict__ out) {
    __shared__ u16 As[128 * LSTR];
    __shared__ u16 Bs[128 * LSTR];

    int orig = blockIdx.x;                       // 8000 = 8 XCDs * 1000
    int w = (orig & 7) * 1000 + (orig >> 3);     // bijective XCD chunking
    int mb = w & 31;                             // 32 m-blocks (== batch b)
    int nb = w >> 5;                             // 250 n-blocks
    int m0 = mb * 128, n0 = nb * 128;

    int tid = threadIdx.x, lane = tid & 63, wid = tid >> 6;
    int wm = wid >> 1, wn = wid & 1;

    f32x4 acc[4][4] = {};

    int srow = tid >> 2;            // 0..63
    int scol = (tid & 3) * 8;       // k-offset within 32-chunk
    const u16* Ag = A + (size_t)(m0 + srow) * H_ + scol;
    const u16* Bg = Wo + (size_t)(n0 + srow) * H_ + scol;

    int kc = (lane >> 4) * 8;
    int frow = lane & 15;

    for (int ks = 0; ks < 32; ++ks) {
        int k0 = ks * 32;
        short8 av0 = *(const short8*)(Ag + k0);
        short8 av1 = *(const short8*)(Ag + (size_t)64 * H_ + k0);
        short8 bv0 = *(const short8*)(Bg + k0);
        short8 bv1 = *(const short8*)(Bg + (size_t)64 * H_ + k0);
        __syncthreads();   // previous iter's frag reads done before overwrite
        *(short8*)(&As[srow * LSTR + scol]) = av0;
        *(short8*)(&As[(srow + 64) * LSTR + scol]) = av1;
        *(short8*)(&Bs[srow * LSTR + scol]) = bv0;
        *(short8*)(&Bs[(srow + 64) * LSTR + scol]) = bv1;
        __syncthreads();

        short8 af[4], bf[4];
#pragma unroll
        for (int mt = 0; mt < 4; ++mt)
            af[mt] = *(const short8*)(&As[(wm * 64 + mt * 16 + frow) * LSTR + kc]);
#pragma unroll
        for (int nt = 0; nt < 4; ++nt)
            bf[nt] = *(const short8*)(&Bs[(wn * 64 + nt * 16 + frow) * LSTR + kc]);
#pragma unroll
        for (int mt = 0; mt < 4; ++mt)
#pragma unroll
            for (int nt = 0; nt < 4; ++nt)
                acc[mt][nt] = __builtin_amdgcn_mfma_f32_16x16x32_bf16(af[mt], bf[nt], acc[mt][nt], 0, 0, 0);
    }

    // Epilogue: C row = t index within batch mb, col = vocab n.
    int b = mb;
#pragma unroll
    for (int nt = 0; nt < 4; ++nt) {
        int n = n0 + wn * 64 + nt * 16 + (lane & 15);
        float bias = bout[n];
#pragma unroll
        for (int mt = 0; mt < 4; ++mt) {
            int trow = wm * 64 + mt * 16 + (lane >> 4) * 4;
            f32x4 v = acc[mt][nt];
            v[0] += bias; v[1] += bias; v[2] += bias; v[3] += bias;
            float* dst = out + ((size_t)b * V_ + n) * T_ + trow;
            *(f32x4*)dst = v;
        }
    }
}

// ---------------------------------------------------------------------------
extern "C" void kernel_launch(void* const* d_in, const int* in_sizes, int n_in,
                              void* d_out, int out_size, void* d_ws, size_t ws_size,
                              hipStream_t stream) {
    const float* y    = (const float*)d_in[0];   // [B,T]
    const float* enc  = (const float*)d_in[1];   // [B,H]
    const float* Wh   = (const float*)d_in[2];   // [H,H]
    const float* Wcp  = (const float*)d_in[3];   // [H,H]
    const float* Wih  = (const float*)d_in[4];   // [4H,1+H]
    const float* Whh  = (const float*)d_in[5];   // [4H,H]
    const float* bih  = (const float*)d_in[6];   // [4H]
    const float* bhh  = (const float*)d_in[7];   // [4H]
    const float* Wout = (const float*)d_in[8];   // [V,H]
    const float* bout = (const float*)d_in[9];   // [V]

    uint8_t* ws = (uint8_t*)d_ws;
    u16*  Wcomb = (u16*)ws;                                   // 4096*1024*2  = 8,388,608
    u16*  Wo    = (u16*)(ws + 8388608);                       // 32000*1024*2 = 65,536,000
    float* wx    = (float*)(ws + 8388608 + 65536000);         // 4096*4
    float* biasc = wx + 4096;                                 // 4096*4
    u16*  h0    = (u16*)(biasc + 4096);                       // 32*1024*2
    float* c     = (float*)(h0 + 32 * 1024);                  // 32*1024*4
    u16*  A     = (u16*)(c + 32 * 1024);                      // 4096*1024*2
    unsigned* bar = (unsigned*)(A + (size_t)4096 * 1024);     // 4 B

    prep_w<<<16384, 256, 0, stream>>>(Wih, Whh, bih, bhh, Wcomb, wx, biasc, bar);
    prep_wout<<<32000, 256, 0, stream>>>(Wout, Wo);
    init_hc<<<16384, 256, 0, stream>>>(enc, Wh, Wcp, h0, c);

    lstm_persist<<<NBLK_REC, 256, 0, stream>>>(Wcomb, wx, biasc, h0, c, y, A, bar);

    gemm_out<<<8000, 256, 0, stream>>>(A, Wo, bout, (float*)d_out);
}